// Round 2
// baseline (12458.942 us; speedup 1.0000x reference)
//
#include <hip/hip_runtime.h>

// EKF, one WAVE (64 lanes) per batch element, 256 single-wave blocks.
// __syncthreads() in a single-wave block is just a waitcnt drain -> all
// cross-wave barrier coupling from R1 is gone. Weight columns of the
// 64x64 matrices (dW1, mW1, dW2) live in per-lane registers; LDS reads
// are broadcast or conflict-free-padded (TL stride 68, T3L stride 36).

#define NB 256
#define NT 512
#define EKF_DT 0.01f
#define PM_OFF (NB * NT * 12)
#define COV_OFF (NB * NT * (12 + 9))

__launch_bounds__(64, 1)
__global__ void ekf_kernel(
    const float* __restrict__ ctrl, const float* __restrict__ meas,
    const float* __restrict__ x0g, const float* __restrict__ P0g,
    const float* __restrict__ Qg, const float* __restrict__ Rg,
    const float* __restrict__ dW0, const float* __restrict__ db0,
    const float* __restrict__ dW1, const float* __restrict__ db1,
    const float* __restrict__ dW2, const float* __restrict__ db2,
    const float* __restrict__ dW3, const float* __restrict__ db3,
    const float* __restrict__ mW0, const float* __restrict__ mb0,
    const float* __restrict__ mW1, const float* __restrict__ mb1,
    const float* __restrict__ mW2, const float* __restrict__ mb2,
    float* __restrict__ out)
{
  const int b = blockIdx.x;
  const int l = threadIdx.x; // 0..63

  __shared__ __align__(16) float sW0[16 * 64];   // rows, broadcast reads
  __shared__ __align__(16) float sM0[12 * 64];
  __shared__ float sW3[32 * 12];
  __shared__ float sM2[64 * 9];
  __shared__ float sQ[144], sR[81];
  __shared__ __align__(16) float A1[64], A1d[64], A2[64];
  __shared__ __align__(16) float A1m[64], A1dm[64], A2m[64];
  __shared__ float A3[32], A3d[32];
  __shared__ __align__(16) float TL[12 * 68];    // T2a then U2a, [i*68+k], padded
  __shared__ __align__(16) float T3L[12 * 36];   // [i*36+k], padded
  __shared__ float Fm[144], Hm[108];
  __shared__ float Pm[144], Pp[144], FPL[144], HPL[108], PHtL[108], SL[81], KL[108], AL[144];
  __shared__ float xsL[12], xpL[12], cuL[4], zvL[9], dvL[9], r4L[12];

  for (int i = l; i < 16 * 64; i += 64) sW0[i] = dW0[i];
  for (int i = l; i < 12 * 64; i += 64) sM0[i] = mW0[i];
  for (int i = l; i < 32 * 12; i += 64) sW3[i] = dW3[i];
  for (int i = l; i < 64 * 9; i += 64) sM2[i] = mW2[i];
  for (int i = l; i < 144; i += 64) { sQ[i] = Qg[i]; Pm[i] = P0g[b * 144 + i]; }
  for (int i = l; i < 81; i += 64) sR[i] = Rg[i];
  if (l < 12) xsL[l] = x0g[b * 12 + l];
  if (l < 9)  zvL[l] = meas[(size_t)(b * NT) * 9 + l];

  // per-lane register weight columns
  float w0c[16], w1c[64], w2c[64], m0c[12], m1c[64];
  #pragma unroll
  for (int k = 0; k < 16; ++k) w0c[k] = dW0[k * 64 + l];
  #pragma unroll
  for (int k = 0; k < 64; ++k) w1c[k] = dW1[k * 64 + l];
  #pragma unroll
  for (int k = 0; k < 64; ++k) w2c[k] = dW2[k * 32 + (l & 31)];
  #pragma unroll
  for (int k = 0; k < 64; ++k) m1c[k] = mW1[k * 64 + l];
  #pragma unroll
  for (int k = 0; k < 12; ++k) m0c[k] = mW0[k * 64 + l];
  const float b0r = db0[l], b1r = db1[l], b2r = db2[l & 31], b3r = db3[l % 12];
  const float n0r = mb0[l], n1r = mb1[l], n2r = mb2[l % 9];

  float cn = 0.f, zn = 0.f;   // prefetch regs for next step's ctrl/meas
  if (l < 4) cn = ctrl[(size_t)(b * NT + 1) * 4 + l];
  if (l < 9) zn = meas[(size_t)(b * NT + 1) * 9 + l];

  __syncthreads();

  float g[64];                // D*column products, reused dyn/meas
  float d2 = 0.f, d2m = 0.f;  // lane-local activation derivatives

  #pragma unroll 1
  for (int t = 0; t < NT; ++t) {
    if (t > 0) {
      // ---- L1 ----
      {
        float pre = b0r;
        #pragma unroll
        for (int k = 0; k < 12; ++k) pre = fmaf(xsL[k], w0c[k], pre);
        #pragma unroll
        for (int k = 0; k < 4; ++k) pre = fmaf(cuL[k], w0c[12 + k], pre);
        const float h = tanhf(pre);
        A1[l] = h; A1d[l] = 1.f - h * h;
      }
      __syncthreads();
      // ---- L2 + g = D1 * w1col ----
      {
        float p0 = b1r, p1 = 0, p2 = 0, p3 = 0;
        #pragma unroll
        for (int k4 = 0; k4 < 16; ++k4) {
          const float4 a = *(const float4*)&A1[4 * k4];
          const float4 d = *(const float4*)&A1d[4 * k4];
          p0 = fmaf(a.x, w1c[4 * k4 + 0], p0);
          p1 = fmaf(a.y, w1c[4 * k4 + 1], p1);
          p2 = fmaf(a.z, w1c[4 * k4 + 2], p2);
          p3 = fmaf(a.w, w1c[4 * k4 + 3], p3);
          g[4 * k4 + 0] = d.x * w1c[4 * k4 + 0];
          g[4 * k4 + 1] = d.y * w1c[4 * k4 + 1];
          g[4 * k4 + 2] = d.z * w1c[4 * k4 + 2];
          g[4 * k4 + 3] = d.w * w1c[4 * k4 + 3];
        }
        const float h = tanhf((p0 + p1) + (p2 + p3));
        A2[l] = h; d2 = 1.f - h * h;
      }
      __syncthreads();
      // ---- L3 (halves duplicate) + T2a[i][lane] ----
      {
        float p0 = b2r, p1 = 0, p2 = 0, p3 = 0;
        #pragma unroll
        for (int k4 = 0; k4 < 16; ++k4) {
          const float4 a = *(const float4*)&A2[4 * k4];
          p0 = fmaf(a.x, w2c[4 * k4 + 0], p0);
          p1 = fmaf(a.y, w2c[4 * k4 + 1], p1);
          p2 = fmaf(a.z, w2c[4 * k4 + 2], p2);
          p3 = fmaf(a.w, w2c[4 * k4 + 3], p3);
        }
        const float h = tanhf((p0 + p1) + (p2 + p3));
        if (l < 32) { A3[l] = h; A3d[l] = 1.f - h * h; }
      }
      #pragma unroll 1
      for (int pr = 0; pr < 6; ++pr) {
        const int i0 = 2 * pr, i1 = i0 + 1;
        float a0 = 0, a1 = 0, c0 = 0, c1 = 0;
        #pragma unroll
        for (int k4 = 0; k4 < 16; ++k4) {
          const float4 r0 = *(const float4*)&sW0[i0 * 64 + 4 * k4];
          const float4 r1 = *(const float4*)&sW0[i1 * 64 + 4 * k4];
          a0 = fmaf(r0.x, g[4 * k4 + 0], a0); a0 = fmaf(r0.y, g[4 * k4 + 1], a0);
          a1 = fmaf(r0.z, g[4 * k4 + 2], a1); a1 = fmaf(r0.w, g[4 * k4 + 3], a1);
          c0 = fmaf(r1.x, g[4 * k4 + 0], c0); c0 = fmaf(r1.y, g[4 * k4 + 1], c0);
          c1 = fmaf(r1.z, g[4 * k4 + 2], c1); c1 = fmaf(r1.w, g[4 * k4 + 3], c1);
        }
        TL[i0 * 68 + l] = (a0 + a1) * d2;
        TL[i1 * 68 + l] = (c0 + c1) * d2;
      }
      __syncthreads();
      // ---- T3a + r4 tail ----
      {
        const int c2 = l & 31, hh = l >> 5, ib = 6 * hh;
        const float d3 = A3d[c2];
        #pragma unroll 1
        for (int pr = 0; pr < 3; ++pr) {
          const int i0 = ib + 2 * pr, i1 = i0 + 1;
          float a0 = 0, a1 = 0, c0 = 0, c1 = 0;
          #pragma unroll
          for (int k4 = 0; k4 < 16; ++k4) {
            const float4 u0 = *(const float4*)&TL[i0 * 68 + 4 * k4];
            const float4 u1 = *(const float4*)&TL[i1 * 68 + 4 * k4];
            a0 = fmaf(u0.x, w2c[4 * k4 + 0], a0); a0 = fmaf(u0.y, w2c[4 * k4 + 1], a0);
            a1 = fmaf(u0.z, w2c[4 * k4 + 2], a1); a1 = fmaf(u0.w, w2c[4 * k4 + 3], a1);
            c0 = fmaf(u1.x, w2c[4 * k4 + 0], c0); c0 = fmaf(u1.y, w2c[4 * k4 + 1], c0);
            c1 = fmaf(u1.z, w2c[4 * k4 + 2], c1); c1 = fmaf(u1.w, w2c[4 * k4 + 3], c1);
          }
          T3L[i0 * 36 + c2] = (a0 + a1) * d3;
          T3L[i1 * 36 + c2] = (c0 + c1) * d3;
        }
        if (l < 12) {
          float acc = b3r;
          #pragma unroll
          for (int k = 0; k < 32; ++k) acc = fmaf(A3[k], sW3[k * 12 + l], acc);
          r4L[l] = acc;
        }
      }
      __syncthreads();
      // ---- F + xp ----
      {
        #pragma unroll 1
        for (int p = 0; p < 3; ++p) {
          const int idx = l + 64 * p;
          if (idx < 144) {
            const int j = idx / 12, i = idx - 12 * j;
            float a0 = 0, a1 = 0;
            #pragma unroll
            for (int k4 = 0; k4 < 8; ++k4) {
              const float4 u = *(const float4*)&T3L[i * 36 + 4 * k4];
              a0 = fmaf(u.x, sW3[(4 * k4 + 0) * 12 + j], a0);
              a0 = fmaf(u.y, sW3[(4 * k4 + 1) * 12 + j], a0);
              a1 = fmaf(u.z, sW3[(4 * k4 + 2) * 12 + j], a1);
              a1 = fmaf(u.w, sW3[(4 * k4 + 3) * 12 + j], a1);
            }
            float v = a0 + a1 + ((i == j) ? 1.f : 0.f);
            if (((j < 3) || (j >= 6 && j < 9)) && (i == j + 3)) v += EKF_DT;
            Fm[idx] = v;
          }
        }
        if (l < 12) {
          const float drift = ((l < 3) || (l >= 6 && l < 9)) ? xsL[l + 3] : 0.f;
          xpL[l] = xsL[l] + EKF_DT * drift + r4L[l];
        }
      }
      __syncthreads();
      // ---- FP = F@P  +  m1 ----
      {
        #pragma unroll 1
        for (int p = 0; p < 3; ++p) {
          const int idx = l + 64 * p;
          if (idx < 144) {
            const int j = idx / 12, c = idx - 12 * j;
            float a0 = 0, a1 = 0;
            #pragma unroll
            for (int m = 0; m < 12; m += 2) {
              a0 = fmaf(Fm[j * 12 + m], Pm[m * 12 + c], a0);
              a1 = fmaf(Fm[j * 12 + m + 1], Pm[(m + 1) * 12 + c], a1);
            }
            FPL[idx] = a0 + a1;
          }
        }
        float pre = n0r;
        #pragma unroll
        for (int k = 0; k < 12; ++k) pre = fmaf(xpL[k], m0c[k], pre);
        A1m[l] = fmaxf(pre, 0.f);
        A1dm[l] = (pre > 0.f) ? 1.f : 0.f;
      }
      __syncthreads();
      // ---- Pp = FP@F^T + Q  +  m2 (+g2) ----
      {
        #pragma unroll 1
        for (int p = 0; p < 3; ++p) {
          const int idx = l + 64 * p;
          if (idx < 144) {
            const int j = idx / 12, c = idx - 12 * j;
            float a0 = sQ[idx], a1 = 0;
            #pragma unroll
            for (int m = 0; m < 12; m += 2) {
              a0 = fmaf(FPL[j * 12 + m], Fm[c * 12 + m], a0);
              a1 = fmaf(FPL[j * 12 + m + 1], Fm[c * 12 + m + 1], a1);
            }
            Pp[idx] = a0 + a1;
          }
        }
        float p0 = n1r, p1 = 0, p2 = 0, p3 = 0;
        #pragma unroll
        for (int k4 = 0; k4 < 16; ++k4) {
          const float4 a = *(const float4*)&A1m[4 * k4];
          const float4 d = *(const float4*)&A1dm[4 * k4];
          p0 = fmaf(a.x, m1c[4 * k4 + 0], p0);
          p1 = fmaf(a.y, m1c[4 * k4 + 1], p1);
          p2 = fmaf(a.z, m1c[4 * k4 + 2], p2);
          p3 = fmaf(a.w, m1c[4 * k4 + 3], p3);
          g[4 * k4 + 0] = d.x * m1c[4 * k4 + 0];
          g[4 * k4 + 1] = d.y * m1c[4 * k4 + 1];
          g[4 * k4 + 2] = d.z * m1c[4 * k4 + 2];
          g[4 * k4 + 3] = d.w * m1c[4 * k4 + 3];
        }
        const float pre = (p0 + p1) + (p2 + p3);
        A2m[l] = fmaxf(pre, 0.f);
        d2m = (pre > 0.f) ? 1.f : 0.f;
      }
      __syncthreads();
    } else {
      // ---- t == 0: xp = x0, Pp = P0, then m1/m2 ----
      if (l < 12) xpL[l] = xsL[l];
      #pragma unroll 1
      for (int p = 0; p < 3; ++p) { const int idx = l + 64 * p; if (idx < 144) Pp[idx] = Pm[idx]; }
      __syncthreads();
      {
        float pre = n0r;
        #pragma unroll
        for (int k = 0; k < 12; ++k) pre = fmaf(xpL[k], m0c[k], pre);
        A1m[l] = fmaxf(pre, 0.f);
        A1dm[l] = (pre > 0.f) ? 1.f : 0.f;
      }
      __syncthreads();
      {
        float pre = n1r;
        #pragma unroll
        for (int k = 0; k < 64; ++k) {
          pre = fmaf(A1m[k], m1c[k], pre);
          g[k] = A1dm[k] * m1c[k];
        }
        A2m[l] = fmaxf(pre, 0.f);
        d2m = (pre > 0.f) ? 1.f : 0.f;
      }
      __syncthreads();
    }
    // ---- U2a + zp tail ----
    #pragma unroll 1
    for (int pr = 0; pr < 6; ++pr) {
      const int i0 = 2 * pr, i1 = i0 + 1;
      float a0 = 0, a1 = 0, c0 = 0, c1 = 0;
      #pragma unroll
      for (int k4 = 0; k4 < 16; ++k4) {
        const float4 r0 = *(const float4*)&sM0[i0 * 64 + 4 * k4];
        const float4 r1 = *(const float4*)&sM0[i1 * 64 + 4 * k4];
        a0 = fmaf(r0.x, g[4 * k4 + 0], a0); a0 = fmaf(r0.y, g[4 * k4 + 1], a0);
        a1 = fmaf(r0.z, g[4 * k4 + 2], a1); a1 = fmaf(r0.w, g[4 * k4 + 3], a1);
        c0 = fmaf(r1.x, g[4 * k4 + 0], c0); c0 = fmaf(r1.y, g[4 * k4 + 1], c0);
        c1 = fmaf(r1.z, g[4 * k4 + 2], c1); c1 = fmaf(r1.w, g[4 * k4 + 3], c1);
      }
      TL[i0 * 68 + l] = (a0 + a1) * d2m;
      TL[i1 * 68 + l] = (c0 + c1) * d2m;
    }
    if (l < 9) {
      float p0 = n2r, p1 = 0, p2 = 0, p3 = 0;
      #pragma unroll
      for (int k4 = 0; k4 < 16; ++k4) {
        const float4 a = *(const float4*)&A2m[4 * k4];
        p0 = fmaf(a.x, sM2[(4 * k4 + 0) * 9 + l], p0);
        p1 = fmaf(a.y, sM2[(4 * k4 + 1) * 9 + l], p1);
        p2 = fmaf(a.z, sM2[(4 * k4 + 2) * 9 + l], p2);
        p3 = fmaf(a.w, sM2[(4 * k4 + 3) * 9 + l], p3);
      }
      const float zpv = xpL[l] + ((p0 + p1) + (p2 + p3));
      dvL[l] = zvL[l] - zpv;
      out[PM_OFF + (size_t)(b * NT + t) * 9 + l] = zpv;
    }
    __syncthreads();
    // ---- H[j][i] ----
    #pragma unroll 1
    for (int p = 0; p < 2; ++p) {
      const int idx = l + 64 * p;
      if (idx < 108) {
        const int i = idx / 9, j = idx - 9 * i;
        float a0 = 0, a1 = 0;
        #pragma unroll
        for (int k4 = 0; k4 < 16; ++k4) {
          const float4 u = *(const float4*)&TL[i * 68 + 4 * k4];
          a0 = fmaf(u.x, sM2[(4 * k4 + 0) * 9 + j], a0);
          a0 = fmaf(u.y, sM2[(4 * k4 + 1) * 9 + j], a0);
          a1 = fmaf(u.z, sM2[(4 * k4 + 2) * 9 + j], a1);
          a1 = fmaf(u.w, sM2[(4 * k4 + 3) * 9 + j], a1);
        }
        Hm[j * 12 + i] = a0 + a1 + ((i == j) ? 1.f : 0.f);
      }
    }
    __syncthreads();
    // ---- HP = H@Pp ; PHt = Pp@H^T ----
    #pragma unroll 1
    for (int p = 0; p < 4; ++p) {
      const int idx = l + 64 * p;
      if (idx < 216) {
        if (idx < 108) {
          const int j = idx / 12, c = idx - 12 * j;
          float a0 = 0, a1 = 0;
          #pragma unroll
          for (int m = 0; m < 12; m += 2) {
            a0 = fmaf(Hm[j * 12 + m], Pp[m * 12 + c], a0);
            a1 = fmaf(Hm[j * 12 + m + 1], Pp[(m + 1) * 12 + c], a1);
          }
          HPL[idx] = a0 + a1;
        } else {
          const int q = idx - 108;
          const int j = q / 9, c = q - 9 * j;
          float a0 = 0, a1 = 0;
          #pragma unroll
          for (int m = 0; m < 12; m += 2) {
            a0 = fmaf(Pp[j * 12 + m], Hm[c * 12 + m], a0);
            a1 = fmaf(Pp[j * 12 + m + 1], Hm[c * 12 + m + 1], a1);
          }
          PHtL[q] = a0 + a1;
        }
      }
    }
    __syncthreads();
    // ---- S = HP@H^T + R ----
    #pragma unroll 1
    for (int p = 0; p < 2; ++p) {
      const int idx = l + 64 * p;
      if (idx < 81) {
        const int a9 = idx / 9, c = idx - 9 * a9;
        float a0 = sR[idx], a1 = 0;
        #pragma unroll
        for (int m = 0; m < 12; m += 2) {
          a0 = fmaf(HPL[a9 * 12 + m], Hm[c * 12 + m], a0);
          a1 = fmaf(HPL[a9 * 12 + m + 1], Hm[c * 12 + m + 1], a1);
        }
        SL[idx] = a0 + a1;
      }
    }
    __syncthreads();
    // ---- K rows via per-lane register Cholesky (12 lanes) ----
    if (l < 12) {
      float Lm[45];
      #pragma unroll
      for (int i = 0; i < 9; ++i)
        #pragma unroll
        for (int j = 0; j <= i; ++j)
          Lm[(i * (i + 1)) / 2 + j] = SL[i * 9 + j];
      #pragma unroll
      for (int k = 0; k < 9; ++k) {
        float d = Lm[(k * (k + 1)) / 2 + k];
        #pragma unroll
        for (int j = 0; j < k; ++j) { const float v = Lm[(k * (k + 1)) / 2 + j]; d -= v * v; }
        d = sqrtf(d);
        Lm[(k * (k + 1)) / 2 + k] = d;
        const float inv = 1.f / d;
        #pragma unroll
        for (int i2 = k + 1; i2 < 9; ++i2) {
          float v = Lm[(i2 * (i2 + 1)) / 2 + k];
          #pragma unroll
          for (int j = 0; j < k; ++j) v -= Lm[(i2 * (i2 + 1)) / 2 + j] * Lm[(k * (k + 1)) / 2 + j];
          Lm[(i2 * (i2 + 1)) / 2 + k] = v * inv;
        }
      }
      float y[9];
      #pragma unroll
      for (int i = 0; i < 9; ++i) {
        float v = PHtL[l * 9 + i];
        #pragma unroll
        for (int j = 0; j < i; ++j) v -= Lm[(i * (i + 1)) / 2 + j] * y[j];
        y[i] = v / Lm[(i * (i + 1)) / 2 + i];
      }
      #pragma unroll
      for (int i = 8; i >= 0; --i) {
        float v = y[i];
        #pragma unroll
        for (int j = i + 1; j < 9; ++j) v -= Lm[(j * (j + 1)) / 2 + i] * y[j];
        y[i] = v / Lm[(i * (i + 1)) / 2 + i];
      }
      #pragma unroll
      for (int i = 0; i < 9; ++i) KL[l * 9 + i] = y[i];
    }
    __syncthreads();
    // ---- A = I - K@H ; x_new + est write ----
    #pragma unroll 1
    for (int p = 0; p < 3; ++p) {
      const int idx = l + 64 * p;
      if (idx < 144) {
        const int j = idx / 12, i = idx - 12 * j;
        float acc = (i == j) ? 1.f : 0.f;
        #pragma unroll
        for (int c = 0; c < 9; ++c) acc -= KL[j * 9 + c] * Hm[c * 12 + i];
        AL[idx] = acc;
      }
    }
    if (l < 12) {
      float acc = xpL[l];
      #pragma unroll
      for (int c = 0; c < 9; ++c) acc = fmaf(KL[l * 9 + c], dvL[c], acc);
      xsL[l] = acc;
      out[(size_t)(b * NT + t) * 12 + l] = acc;
    }
    __syncthreads();
    // ---- P_new = A@Pp + cov write ; prefetch rotate ----
    #pragma unroll 1
    for (int p = 0; p < 3; ++p) {
      const int idx = l + 64 * p;
      if (idx < 144) {
        const int j = idx / 12, c = idx - 12 * j;
        float a0 = 0, a1 = 0;
        #pragma unroll
        for (int m = 0; m < 12; m += 2) {
          a0 = fmaf(AL[j * 12 + m], Pp[m * 12 + c], a0);
          a1 = fmaf(AL[j * 12 + m + 1], Pp[(m + 1) * 12 + c], a1);
        }
        const float v = a0 + a1;
        Pm[idx] = v;
        out[COV_OFF + (size_t)(b * NT + t) * 144 + idx] = v;
      }
    }
    if (l < 4) cuL[l] = cn;
    if (l < 9) zvL[l] = zn;
    {
      const int tn = (t + 2 < NT) ? (t + 2) : (NT - 1);
      if (l < 4) cn = ctrl[(size_t)(b * NT + tn) * 4 + l];
      if (l < 9) zn = meas[(size_t)(b * NT + tn) * 9 + l];
    }
    __syncthreads();
  }
}

extern "C" void kernel_launch(void* const* d_in, const int* in_sizes, int n_in,
                              void* d_out, int out_size, void* d_ws, size_t ws_size,
                              hipStream_t stream) {
  (void)in_sizes; (void)n_in; (void)d_ws; (void)ws_size; (void)out_size;
  ekf_kernel<<<NB, 64, 0, stream>>>(
      (const float*)d_in[1], (const float*)d_in[2],
      (const float*)d_in[3], (const float*)d_in[4],
      (const float*)d_in[5], (const float*)d_in[6],
      (const float*)d_in[7], (const float*)d_in[8],
      (const float*)d_in[9], (const float*)d_in[10],
      (const float*)d_in[11], (const float*)d_in[12],
      (const float*)d_in[13], (const float*)d_in[14],
      (const float*)d_in[15], (const float*)d_in[16],
      (const float*)d_in[17], (const float*)d_in[18],
      (const float*)d_in[19], (const float*)d_in[20],
      (float*)d_out);
}

// Round 4
// 4022.715 us; speedup vs baseline: 3.0971x; 3.0971x over previous
//
#include <hip/hip_runtime.h>

// EKF, 4 waves (256 thr) per batch element, 256 blocks = 1/CU (R1 topology).
// vs R1: stride-20 tangent layouts (fixes 32-way write conflicts),
// S = H@(P H^T) (HP phase dropped), forward-MLP tail & measurement MLP run on
// wave 3 inside the big tangent phases, fast tanh (__expf), rsqrt Cholesky,
// and est/cov writes + input prefetch hidden under the solve phase.

#define NB 256
#define NT 512
#define EKF_DT 0.01f
#define PM_OFF (NB * NT * 12)
#define COV_OFF (NB * NT * (12 + 9))

__device__ __forceinline__ float fast_tanh(float x) {
  const float ax = fabsf(x);
  const float e = __expf(-2.f * ax);
  const float t = 1.f - 2.f * e * __builtin_amdgcn_rcpf(1.f + e);
  return copysignf(t, x);
}

__launch_bounds__(256, 1)
__global__ void ekf_kernel(
    const float* __restrict__ ctrl, const float* __restrict__ meas,
    const float* __restrict__ x0g, const float* __restrict__ P0g,
    const float* __restrict__ Qg, const float* __restrict__ Rg,
    const float* __restrict__ dW0, const float* __restrict__ db0,
    const float* __restrict__ dW1, const float* __restrict__ db1,
    const float* __restrict__ dW2, const float* __restrict__ db2,
    const float* __restrict__ dW3, const float* __restrict__ db3,
    const float* __restrict__ mW0, const float* __restrict__ mb0,
    const float* __restrict__ mW1, const float* __restrict__ mb1,
    const float* __restrict__ mW2, const float* __restrict__ mb2,
    float* __restrict__ out)
{
  const int b = blockIdx.x;
  const int tid = threadIdx.x;
  const int l = tid & 63;
  const int wid = tid >> 6;

  __shared__ __align__(16) float sW0[16 * 64];
  __shared__ float sW2[64 * 32];
  __shared__ float sW3[32 * 12];
  __shared__ __align__(16) float sM0[12 * 64];
  __shared__ float sM2[64 * 9];
  __shared__ float sQ[144], sR[81];
  __shared__ __align__(16) float A1[64], A1d[64], A2[64], A2d[64];
  __shared__ float A3[32], A3d[32];
  __shared__ __align__(16) float A1m[64], A2m[64], A2dm[64];
  // tangent fragments, [k][i] with stride 20 (16B-aligned, covers all banks)
  __shared__ __align__(16) float R1t[64 * 20]; // T1t / U1t
  __shared__ __align__(16) float R2t[64 * 20]; // T2t / U2t
  __shared__ __align__(16) float R3t[32 * 20]; // T3t
  __shared__ float Fm[144], Hm[108];
  __shared__ float FPL[144], PHtL[108], SL[81], KL[108], AL[144];
  __shared__ float Pm[144], Pp[144];
  __shared__ float xsL[12], xpL[12], cuL[4], zvL[9], dvL[9];

  for (int i = tid; i < 16 * 64; i += 256) sW0[i] = dW0[i];
  for (int i = tid; i < 64 * 32; i += 256) sW2[i] = dW2[i];
  for (int i = tid; i < 32 * 12; i += 256) sW3[i] = dW3[i];
  for (int i = tid; i < 12 * 64; i += 256) sM0[i] = mW0[i];
  for (int i = tid; i < 64 * 9; i += 256) sM2[i] = mW2[i];
  if (tid < 144) { sQ[tid] = Qg[tid]; Pm[tid] = P0g[b * 144 + tid]; }
  if (tid >= 160 && tid < 241) sR[tid - 160] = Rg[tid - 160];
  if (tid < 12) xsL[tid] = x0g[b * 12 + tid];
  if (tid >= 32 && tid < 41) zvL[tid - 32] = meas[(size_t)(b * NT) * 9 + (tid - 32)];

  const float b0r = db0[l], b1r = db1[l], b2r = db2[l & 31], b3r = db3[l % 12];
  const float n0r = mb0[l], n1r = mb1[l], n2r = mb2[l % 9];

  // per-lane register columns of the two 64x64 weights
  float w1c[64], m1c[64];
  #pragma unroll
  for (int k = 0; k < 64; ++k) { w1c[k] = dW1[k * 64 + l]; m1c[k] = mW1[k * 64 + l]; }
  __syncthreads();

  #pragma unroll 1
  for (int t = 0; t < NT; ++t) {
    if (t > 0) {
      // ---- B: L1 (wave 0) ----
      if (wid == 0) {
        float pre = b0r;
        #pragma unroll
        for (int k = 0; k < 12; ++k) pre = fmaf(xsL[k], sW0[k * 64 + l], pre);
        #pragma unroll
        for (int k = 0; k < 4; ++k) pre = fmaf(cuL[k], sW0[(12 + k) * 64 + l], pre);
        const float h = fast_tanh(pre);
        A1[l] = h; A1d[l] = 1.f - h * h;
      }
      __syncthreads();
      // ---- C: L2 (wave 0) | T1t (waves 1-3) ----
      if (wid == 0) {
        float p0 = b1r, p1 = 0, p2 = 0, p3 = 0;
        #pragma unroll
        for (int k4 = 0; k4 < 16; ++k4) {
          const float4 a = *(const float4*)&A1[4 * k4];
          p0 = fmaf(a.x, w1c[4 * k4 + 0], p0);
          p1 = fmaf(a.y, w1c[4 * k4 + 1], p1);
          p2 = fmaf(a.z, w1c[4 * k4 + 2], p2);
          p3 = fmaf(a.w, w1c[4 * k4 + 3], p3);
        }
        const float h = fast_tanh((p0 + p1) + (p2 + p3));
        A2[l] = h; A2d[l] = 1.f - h * h;
      } else {
        const int q = tid - 64, k = q & 63, j = q >> 6; // j = i-quad 0..2
        const float d = A1d[k];
        float4 o;
        o.x = d * sW0[(4 * j + 0) * 64 + k];
        o.y = d * sW0[(4 * j + 1) * 64 + k];
        o.z = d * sW0[(4 * j + 2) * 64 + k];
        o.w = d * sW0[(4 * j + 3) * 64 + k];
        *(float4*)&R1t[k * 20 + 4 * j] = o;
      }
      __syncthreads();
      // ---- D: T2 (waves 0-2) | L3 -> r4 -> xp (wave 3) ----
      if (wid < 3) {
        float a0 = 0, a1 = 0, a2 = 0, a3 = 0;
        #pragma unroll
        for (int k = 0; k < 64; ++k) {
          const float4 tt = *(const float4*)&R1t[k * 20 + 4 * wid];
          const float w = w1c[k];
          a0 = fmaf(tt.x, w, a0); a1 = fmaf(tt.y, w, a1);
          a2 = fmaf(tt.z, w, a2); a3 = fmaf(tt.w, w, a3);
        }
        const float d = A2d[l];
        float4 o; o.x = a0 * d; o.y = a1 * d; o.z = a2 * d; o.w = a3 * d;
        *(float4*)&R2t[l * 20 + 4 * wid] = o;
      } else {
        if (l < 32) {
          float p0 = b2r, p1 = 0, p2 = 0, p3 = 0;
          #pragma unroll
          for (int k = 0; k < 64; k += 4) {
            p0 = fmaf(A2[k + 0], sW2[(k + 0) * 32 + l], p0);
            p1 = fmaf(A2[k + 1], sW2[(k + 1) * 32 + l], p1);
            p2 = fmaf(A2[k + 2], sW2[(k + 2) * 32 + l], p2);
            p3 = fmaf(A2[k + 3], sW2[(k + 3) * 32 + l], p3);
          }
          const float h = fast_tanh((p0 + p1) + (p2 + p3));
          A3[l] = h; A3d[l] = 1.f - h * h;
        }
        if (l < 12) {
          float a0 = b3r, a1 = 0;
          #pragma unroll
          for (int k = 0; k < 32; k += 2) {
            a0 = fmaf(A3[k], sW3[k * 12 + l], a0);
            a1 = fmaf(A3[k + 1], sW3[(k + 1) * 12 + l], a1);
          }
          const float r4 = a0 + a1;
          const float drift = ((l < 3) || (l >= 6 && l < 9)) ? xsL[l + 3] : 0.f;
          xpL[l] = xsL[l] + EKF_DT * drift + r4;
        }
      }
      __syncthreads();
    } else {
      // ---- t==0: xp = x0, Pp = P0 ----
      if (tid < 12) xpL[tid] = xsL[tid];
      if (tid < 144) Pp[tid] = Pm[tid];
      __syncthreads();
    }
    // ---- E: T3 (waves 0-2, t>0) | m1 -> m2 -> U1t (wave 3) ----
    if (wid < 3) {
      if (t > 0) {
        const int c2 = l & 31, hh = l >> 5;
        float a0 = 0, a1 = 0, a2 = 0, a3 = 0;
        #pragma unroll
        for (int kk = 0; kk < 32; ++kk) {
          const int k = hh * 32 + kk;
          const float4 tt = *(const float4*)&R2t[k * 20 + 4 * wid];
          const float w = sW2[k * 32 + c2];
          a0 = fmaf(tt.x, w, a0); a1 = fmaf(tt.y, w, a1);
          a2 = fmaf(tt.z, w, a2); a3 = fmaf(tt.w, w, a3);
        }
        a0 += __shfl_down(a0, 32); a1 += __shfl_down(a1, 32);
        a2 += __shfl_down(a2, 32); a3 += __shfl_down(a3, 32);
        if (hh == 0) {
          const float d = A3d[c2];
          float4 o; o.x = a0 * d; o.y = a1 * d; o.z = a2 * d; o.w = a3 * d;
          *(float4*)&R3t[c2 * 20 + 4 * wid] = o;
        }
      }
    } else {
      // m1 (12-k matvec from xp)
      float pre = n0r;
      #pragma unroll
      for (int k = 0; k < 12; ++k) pre = fmaf(xpL[k], sM0[k * 64 + l], pre);
      const float d1m = (pre > 0.f) ? 1.f : 0.f;
      A1m[l] = fmaxf(pre, 0.f);
      // m2 (same-wave DS ordering makes A1m visible)
      float p0 = n1r, p1 = 0, p2 = 0, p3 = 0;
      #pragma unroll
      for (int k4 = 0; k4 < 16; ++k4) {
        const float4 a = *(const float4*)&A1m[4 * k4];
        p0 = fmaf(a.x, m1c[4 * k4 + 0], p0);
        p1 = fmaf(a.y, m1c[4 * k4 + 1], p1);
        p2 = fmaf(a.z, m1c[4 * k4 + 2], p2);
        p3 = fmaf(a.w, m1c[4 * k4 + 3], p3);
      }
      const float pre2 = (p0 + p1) + (p2 + p3);
      A2m[l] = fmaxf(pre2, 0.f);
      A2dm[l] = (pre2 > 0.f) ? 1.f : 0.f;
      // U1t
      #pragma unroll
      for (int j = 0; j < 3; ++j) {
        float4 o;
        o.x = d1m * sM0[(4 * j + 0) * 64 + l];
        o.y = d1m * sM0[(4 * j + 1) * 64 + l];
        o.z = d1m * sM0[(4 * j + 2) * 64 + l];
        o.w = d1m * sM0[(4 * j + 3) * 64 + l];
        *(float4*)&R1t[l * 20 + 4 * j] = o;
      }
    }
    __syncthreads();
    // ---- F: F-matrix (tid<144, t>0) | zp/dv/pred-write (wave 3, l<9) ----
    if (tid < 144) {
      if (t > 0) {
        const int i = tid / 12, j = tid - 12 * i;
        float a0 = 0, a1 = 0;
        #pragma unroll
        for (int k = 0; k < 32; k += 2) {
          a0 = fmaf(R3t[k * 20 + i], sW3[k * 12 + j], a0);
          a1 = fmaf(R3t[(k + 1) * 20 + i], sW3[(k + 1) * 12 + j], a1);
        }
        float v = a0 + a1 + ((i == j) ? 1.f : 0.f);
        if (((j < 3) || (j >= 6 && j < 9)) && (i == j + 3)) v += EKF_DT;
        Fm[j * 12 + i] = v;
      }
    } else if (wid == 3 && l < 9) {
      float p0 = n2r, p1 = 0, p2 = 0, p3 = 0;
      #pragma unroll
      for (int k4 = 0; k4 < 16; ++k4) {
        const float4 a = *(const float4*)&A2m[4 * k4];
        p0 = fmaf(a.x, sM2[(4 * k4 + 0) * 9 + l], p0);
        p1 = fmaf(a.y, sM2[(4 * k4 + 1) * 9 + l], p1);
        p2 = fmaf(a.z, sM2[(4 * k4 + 2) * 9 + l], p2);
        p3 = fmaf(a.w, sM2[(4 * k4 + 3) * 9 + l], p3);
      }
      const float zpv = xpL[l] + ((p0 + p1) + (p2 + p3));
      dvL[l] = zvL[l] - zpv;
      out[PM_OFF + (size_t)(b * NT + t) * 9 + l] = zpv;
    }
    __syncthreads();
    // ---- G: U2 (waves 0-2) | FP = F@P (wave 3, t>0) ----
    if (wid < 3) {
      float a0 = 0, a1 = 0, a2 = 0, a3 = 0;
      #pragma unroll
      for (int k = 0; k < 64; ++k) {
        const float4 tt = *(const float4*)&R1t[k * 20 + 4 * wid];
        const float w = m1c[k];
        a0 = fmaf(tt.x, w, a0); a1 = fmaf(tt.y, w, a1);
        a2 = fmaf(tt.z, w, a2); a3 = fmaf(tt.w, w, a3);
      }
      const float d = A2dm[l];
      float4 o; o.x = a0 * d; o.y = a1 * d; o.z = a2 * d; o.w = a3 * d;
      *(float4*)&R2t[l * 20 + 4 * wid] = o;
    } else if (t > 0) {
      #pragma unroll 1
      for (int p = 0; p < 3; ++p) {
        const int idx = 64 * p + l;
        if (idx < 144) {
          const int j = idx / 12, c = idx - 12 * j;
          float a0 = 0, a1 = 0;
          #pragma unroll
          for (int m = 0; m < 12; m += 2) {
            a0 = fmaf(Fm[j * 12 + m], Pm[m * 12 + c], a0);
            a1 = fmaf(Fm[j * 12 + m + 1], Pm[(m + 1) * 12 + c], a1);
          }
          FPL[idx] = a0 + a1;
        }
      }
    }
    __syncthreads();
    // ---- H: H-matrix (tid<108) | Pp = FP@F^T + Q (wave 3, t>0) ----
    if (tid < 108) {
      const int i = tid / 9, j = tid - 9 * i;
      float a0 = 0, a1 = 0;
      #pragma unroll
      for (int k = 0; k < 64; k += 2) {
        a0 = fmaf(R2t[k * 20 + i], sM2[k * 9 + j], a0);
        a1 = fmaf(R2t[(k + 1) * 20 + i], sM2[(k + 1) * 9 + j], a1);
      }
      Hm[j * 12 + i] = a0 + a1 + ((i == j) ? 1.f : 0.f);
    } else if (wid == 3 && t > 0) {
      #pragma unroll 1
      for (int p = 0; p < 3; ++p) {
        const int idx = 64 * p + l;
        if (idx < 144) {
          const int j = idx / 12, c = idx - 12 * j;
          float a0 = sQ[idx], a1 = 0;
          #pragma unroll
          for (int m = 0; m < 12; m += 2) {
            a0 = fmaf(FPL[j * 12 + m], Fm[c * 12 + m], a0);
            a1 = fmaf(FPL[j * 12 + m + 1], Fm[c * 12 + m + 1], a1);
          }
          Pp[idx] = a0 + a1;
        }
      }
    }
    __syncthreads();
    // ---- I: PHt = Pp@H^T (tid<108) ----
    if (tid < 108) {
      const int j = tid / 9, c = tid - 9 * j;
      float a0 = 0, a1 = 0;
      #pragma unroll
      for (int m = 0; m < 12; m += 2) {
        a0 = fmaf(Pp[j * 12 + m], Hm[c * 12 + m], a0);
        a1 = fmaf(Pp[j * 12 + m + 1], Hm[c * 12 + m + 1], a1);
      }
      PHtL[j * 9 + c] = a0 + a1;
    }
    __syncthreads();
    // ---- J: S = H@PHt + R (tid<81) ----
    if (tid < 81) {
      const int a9 = tid / 9, c = tid - 9 * a9;
      float a0 = sR[tid], a1 = 0;
      #pragma unroll
      for (int m = 0; m < 12; m += 2) {
        a0 = fmaf(Hm[a9 * 12 + m], PHtL[m * 9 + c], a0);
        a1 = fmaf(Hm[(a9) * 12 + m + 1], PHtL[(m + 1) * 9 + c], a1);
      }
      SL[tid] = a0 + a1;
    }
    __syncthreads();
    // ---- K: solve (lanes 0-11 of wave 0) | deferred writes + prefetch ----
    if (tid < 12) {
      float Lm[45], invd[9];
      #pragma unroll
      for (int i = 0; i < 9; ++i)
        #pragma unroll
        for (int j = 0; j <= i; ++j)
          Lm[(i * (i + 1)) / 2 + j] = SL[i * 9 + j];
      #pragma unroll
      for (int k = 0; k < 9; ++k) {
        float d = Lm[(k * (k + 1)) / 2 + k];
        #pragma unroll
        for (int j = 0; j < k; ++j) { const float v = Lm[(k * (k + 1)) / 2 + j]; d -= v * v; }
        float rs = __frsqrt_rn(d);
        rs = rs * (1.5f - 0.5f * d * rs * rs);  // one Newton step
        Lm[(k * (k + 1)) / 2 + k] = d * rs;
        invd[k] = rs;
        #pragma unroll
        for (int i2 = k + 1; i2 < 9; ++i2) {
          float v = Lm[(i2 * (i2 + 1)) / 2 + k];
          #pragma unroll
          for (int j = 0; j < k; ++j) v -= Lm[(i2 * (i2 + 1)) / 2 + j] * Lm[(k * (k + 1)) / 2 + j];
          Lm[(i2 * (i2 + 1)) / 2 + k] = v * rs;
        }
      }
      float y[9];
      #pragma unroll
      for (int i = 0; i < 9; ++i) {
        float v = PHtL[tid * 9 + i];
        #pragma unroll
        for (int j = 0; j < i; ++j) v -= Lm[(i * (i + 1)) / 2 + j] * y[j];
        y[i] = v * invd[i];
      }
      #pragma unroll
      for (int i = 8; i >= 0; --i) {
        float v = y[i];
        #pragma unroll
        for (int j = i + 1; j < 9; ++j) v -= Lm[(j * (j + 1)) / 2 + i] * y[j];
        y[i] = v * invd[i];
      }
      #pragma unroll
      for (int i = 0; i < 9; ++i) KL[tid * 9 + i] = y[i];
    }
    if (tid >= 64 && t > 0) {
      const int idx = tid - 64;
      if (idx < 144) out[COV_OFF + (size_t)(b * NT + (t - 1)) * 144 + idx] = Pm[idx];
      else if (idx < 156) out[(size_t)(b * NT + (t - 1)) * 12 + (idx - 144)] = xsL[idx - 144];
    }
    if (tid >= 224) {
      const int tn = (t + 1 < NT) ? (t + 1) : (NT - 1);
      if (tid < 228) cuL[tid - 224] = ctrl[(size_t)(b * NT + tn) * 4 + (tid - 224)];
      else if (tid >= 232 && tid < 241) zvL[tid - 232] = meas[(size_t)(b * NT + tn) * 9 + (tid - 232)];
    }
    __syncthreads();
    // ---- L: A = I - K@H (tid<144) | x_new (tid 144-155) ----
    if (tid < 144) {
      const int j = tid / 12, i = tid - 12 * j;
      float acc = (i == j) ? 1.f : 0.f;
      #pragma unroll
      for (int c = 0; c < 9; ++c) acc -= KL[j * 9 + c] * Hm[c * 12 + i];
      AL[tid] = acc;
    } else if (tid < 156) {
      const int j = tid - 144;
      float acc = xpL[j];
      #pragma unroll
      for (int c = 0; c < 9; ++c) acc = fmaf(KL[j * 9 + c], dvL[c], acc);
      xsL[j] = acc;
    }
    __syncthreads();
    // ---- M: P_new = A@Pp -> Pm (global write deferred) ----
    if (tid < 144) {
      const int j = tid / 12, c = tid - 12 * j;
      float a0 = 0, a1 = 0;
      #pragma unroll
      for (int m = 0; m < 12; m += 2) {
        a0 = fmaf(AL[j * 12 + m], Pp[m * 12 + c], a0);
        a1 = fmaf(AL[j * 12 + m + 1], Pp[(m + 1) * 12 + c], a1);
      }
      Pm[tid] = a0 + a1;
    }
    __syncthreads();
  }
  // final step's deferred writes
  if (tid < 144) out[COV_OFF + (size_t)(b * NT + (NT - 1)) * 144 + tid] = Pm[tid];
  else if (tid < 156) out[(size_t)(b * NT + (NT - 1)) * 12 + (tid - 144)] = xsL[tid - 144];
}

extern "C" void kernel_launch(void* const* d_in, const int* in_sizes, int n_in,
                              void* d_out, int out_size, void* d_ws, size_t ws_size,
                              hipStream_t stream) {
  (void)in_sizes; (void)n_in; (void)d_ws; (void)ws_size; (void)out_size;
  ekf_kernel<<<NB, 256, 0, stream>>>(
      (const float*)d_in[1], (const float*)d_in[2],
      (const float*)d_in[3], (const float*)d_in[4],
      (const float*)d_in[5], (const float*)d_in[6],
      (const float*)d_in[7], (const float*)d_in[8],
      (const float*)d_in[9], (const float*)d_in[10],
      (const float*)d_in[11], (const float*)d_in[12],
      (const float*)d_in[13], (const float*)d_in[14],
      (const float*)d_in[15], (const float*)d_in[16],
      (const float*)d_in[17], (const float*)d_in[18],
      (const float*)d_in[19], (const float*)d_in[20],
      (float*)d_out);
}